// Round 7
// baseline (186.889 us; speedup 1.0000x reference)
//
#include <hip/hip_runtime.h>
#include <hip/hip_fp16.h>

// AggregationLayer: out[n, :] = mean over {e : segment_ids[e]==n} of src[gather_idx[e], :]
// N=100000, E=3200000, D=32 fp32. segment_ids SORTED.
//
// Kernel A (prep): segment boundaries start[n]; fp16 split of src into hsrcA (features
//   0..15) and hsrcB (16..31), 3.2 MB each (< 4 MB per-XCD L2); zero the 2 work queues.
// Kernel B (main): persistent blocks read HW_REG_XCC_ID; XCDs 0-3 drain queue A
//   (gather from hsrcA), XCDs 4-7 queue B, then STEAL from the other queue (correct
//   under any XCD mapping). Each XCD's L2 caches only its 3.2 MB half => gathers ~all
//   L2-hit. 2-lane groups (16 B loads, 1 line-request per edge per half), unroll x8,
//   fp32 accumulate. gidx/start/out use nontemporal ops to keep L2 for the table.

constexpr int D  = 32;
constexpr int HD = 16;                          // features per half
constexpr int BLOCK = 256;
constexpr int SEGS_PER_CLAIM = BLOCK / 2;       // 2 lanes/segment -> 128 segs per claim
constexpr int GRID_MAIN = 2048;                 // 8 blocks/CU equivalent; work-queue fed

typedef _Float16 half8 __attribute__((ext_vector_type(8)));
typedef float    f32x4 __attribute__((ext_vector_type(4)));   // clang vector: OK for nontemporal

__global__ __launch_bounds__(BLOCK) void prep_kernel(
    const float* __restrict__ src,
    const int*   __restrict__ segid,
    int*         __restrict__ q,       // 2 queue counters
    int*         __restrict__ start,   // N+1 entries
    _Float16*    __restrict__ hsrcA,   // N*16 halfs (features 0..15)
    _Float16*    __restrict__ hsrcB,   // N*16 halfs (features 16..31)
    int E, int N)
{
    const int t = blockIdx.x * BLOCK + threadIdx.x;

    if (t < 2) q[t] = 0;               // work-queue counters (ws is poisoned 0xAA)

    // --- segment boundaries (one coalesced pass over segid) ---
    if (t <= E) {
        int s, p;
        if (t == E) { s = N; p = segid[E - 1]; }
        else        { s = segid[t]; p = (t == 0) ? -1 : segid[t - 1]; }
        for (int n = p + 1; n <= s; ++n) start[n] = t;   // usually 0 or 1 iters
    }

    // --- fp32 -> fp16 split copy: thread t<N does row t half A, t in [N,2N) half B ---
    if (t < 2 * N) {
        const int  row  = (t < N) ? t : t - N;
        const int  hoff = (t < N) ? 0 : HD;
        _Float16*  dst  = (t < N) ? hsrcA : hsrcB;
        const float* sp = src + (size_t)row * D + hoff;
        const float4 a = *(const float4*)(sp);
        const float4 b = *(const float4*)(sp + 4);
        const float4 c = *(const float4*)(sp + 8);
        const float4 d = *(const float4*)(sp + 12);
        half8 h0, h1;
        h0[0] = (_Float16)a.x; h0[1] = (_Float16)a.y; h0[2] = (_Float16)a.z; h0[3] = (_Float16)a.w;
        h0[4] = (_Float16)b.x; h0[5] = (_Float16)b.y; h0[6] = (_Float16)b.z; h0[7] = (_Float16)b.w;
        h1[0] = (_Float16)c.x; h1[1] = (_Float16)c.y; h1[2] = (_Float16)c.z; h1[3] = (_Float16)c.w;
        h1[4] = (_Float16)d.x; h1[5] = (_Float16)d.y; h1[6] = (_Float16)d.z; h1[7] = (_Float16)d.w;
        *(half8*)(dst + (size_t)row * HD)     = h0;
        *(half8*)(dst + (size_t)row * HD + 8) = h1;
    }
}

__global__ __launch_bounds__(BLOCK) void AggregationLayer_53051436040325_kernel(
    const _Float16* __restrict__ hsrcA,
    const _Float16* __restrict__ hsrcB,
    const int*      __restrict__ gidx,
    const int*      __restrict__ start,
    int*            __restrict__ q,
    float*          __restrict__ out,
    int N)
{
    __shared__ int s_c;

    int xcc;
    asm volatile("s_getreg_b32 %0, hwreg(HW_REG_XCC_ID)" : "=s"(xcc));
    const int my = (xcc >> 2) & 1;              // XCDs 0-3 -> half A, 4-7 -> half B

    const int segoff = threadIdx.x >> 1;        // 0..127
    const int sub    = threadIdx.x & 1;         // 8-feature slot within the half

    for (int pass = 0; pass < 2; ++pass) {
        const int h = my ^ pass;                // own half first, then steal
        const _Float16* __restrict__ table = h ? hsrcB : hsrcA;
        int* qq = q + h;

        while (true) {
            if (threadIdx.x == 0) s_c = atomicAdd(qq, 1);
            __syncthreads();
            const int n0 = s_c * SEGS_PER_CLAIM;
            __syncthreads();                    // s_c consumed before next overwrite
            if (n0 >= N) break;                 // uniform across block

            const int n = n0 + segoff;
            if (n < N) {
                const int lo = __builtin_nontemporal_load(start + n);
                const int hi = __builtin_nontemporal_load(start + n + 1);
                const _Float16* sp = table + sub * 8;

                float acc[8];
#pragma unroll
                for (int j = 0; j < 8; ++j) acc[j] = 0.f;

                int e = lo;
                // Unroll x8: 8 independent idx->gather dependent-load chains in flight.
                for (; e + 8 <= hi; e += 8) {
                    int g[8];
#pragma unroll
                    for (int k = 0; k < 8; ++k) g[k] = __builtin_nontemporal_load(gidx + e + k);
                    half8 v[8];
#pragma unroll
                    for (int k = 0; k < 8; ++k) v[k] = *(const half8*)(sp + (size_t)g[k] * HD);
#pragma unroll
                    for (int k = 0; k < 8; ++k)
#pragma unroll
                        for (int j = 0; j < 8; ++j) acc[j] += (float)v[k][j];
                }
                for (; e < hi; ++e) {
                    const int g = __builtin_nontemporal_load(gidx + e);
                    const half8 v = *(const half8*)(sp + (size_t)g * HD);
#pragma unroll
                    for (int j = 0; j < 8; ++j) acc[j] += (float)v[j];
                }

                const int cnt = hi - lo;
                const float inv = 1.f / (float)(cnt > 0 ? cnt : 1);   // max(count,1)
                f32x4 r0 = { acc[0] * inv, acc[1] * inv, acc[2] * inv, acc[3] * inv };
                f32x4 r1 = { acc[4] * inv, acc[5] * inv, acc[6] * inv, acc[7] * inv };
                float* op = out + (size_t)n * D + h * HD + sub * 8;
                __builtin_nontemporal_store(r0, (f32x4*)(op));
                __builtin_nontemporal_store(r1, (f32x4*)(op + 4));
            }
        }
    }
}

extern "C" void kernel_launch(void* const* d_in, const int* in_sizes, int n_in,
                              void* d_out, int out_size, void* d_ws, size_t ws_size,
                              hipStream_t stream) {
    const float* src   = (const float*)d_in[0];
    const int*   gidx  = (const int*)d_in[1];
    const int*   segid = (const int*)d_in[2];
    const int E = in_sizes[1];
    const int N = in_sizes[0] / D;       // == out_size / D

    // ws layout: q[2] ints | start[N+1] ints | hsrcA[N*16] | hsrcB[N*16] (fp16)
    char* ws = (char*)d_ws;
    int* q = (int*)ws;
    size_t off = 256;
    int* start = (int*)(ws + off);
    off += ((size_t)(N + 1) * sizeof(int) + 255) & ~(size_t)255;
    _Float16* hsrcA = (_Float16*)(ws + off);
    off += ((size_t)N * HD * sizeof(_Float16) + 255) & ~(size_t)255;
    _Float16* hsrcB = (_Float16*)(ws + off);

    float* out = (float*)d_out;

    const int threadsA = (E + 1 > 2 * N) ? (E + 1) : (2 * N);
    const int blocksA = (threadsA + BLOCK - 1) / BLOCK;
    prep_kernel<<<blocksA, BLOCK, 0, stream>>>(src, segid, q, start, hsrcA, hsrcB, E, N);

    AggregationLayer_53051436040325_kernel<<<GRID_MAIN, BLOCK, 0, stream>>>(
        hsrcA, hsrcB, gidx, start, q, out, N);
}

// Round 9
// 133.025 us; speedup vs baseline: 1.4049x; 1.4049x over previous
//
#include <hip/hip_runtime.h>
#include <hip/hip_fp16.h>

// AggregationLayer: out[n, :] = mean over {e : segment_ids[e]==n} of src[gather_idx[e], :]
// N=100000, E=3200000, D=32 fp32. segment_ids SORTED.
//
// R8 (revert to best-known R3 structure + L2 stream separation):
//  prep: segment boundaries start[n] + fp16 convert of src into ONE table (64 B rows).
//  main: 4-lane group per segment (4 x half8 = one coalesced 64 B line request per edge),
//        unroll x8 with int4-vectorized gidx loads. Streams (gidx, start, out) use
//        nontemporal hints so the 6.4 MB gather table keeps the per-XCD 4 MB L2.

constexpr int D  = 32;
constexpr int GSZ = 4;                         // lanes per segment group
constexpr int BLOCK = 256;
constexpr int SEGS_PER_BLOCK = BLOCK / GSZ;    // 64 segments per block

typedef _Float16 half8 __attribute__((ext_vector_type(8)));
typedef float    f32x4 __attribute__((ext_vector_type(4)));
typedef int      int4a __attribute__((ext_vector_type(4)));

__global__ __launch_bounds__(BLOCK) void prep_kernel(
    const float* __restrict__ src,
    const int*   __restrict__ segid,
    int*         __restrict__ start,   // N+1 entries
    _Float16*    __restrict__ hsrc,    // N*32 halfs (64 B rows)
    int E, int N)
{
    const int t = blockIdx.x * BLOCK + threadIdx.x;

    // --- segment boundaries (one coalesced pass over segid) ---
    if (t <= E) {
        int s, p;
        if (t == E) { s = N; p = segid[E - 1]; }
        else        { s = segid[t]; p = (t == 0) ? -1 : segid[t - 1]; }
        for (int n = p + 1; n <= s; ++n) start[n] = t;   // usually 0 or 1 iters
    }

    // --- fp32 -> fp16 convert: thread t handles 16 features (32 B) ---
    if (t < 2 * N) {
        const int row  = t >> 1;
        const int hoff = (t & 1) * 16;
        const float* sp = src + (size_t)row * D + hoff;
        const float4 a = *(const float4*)(sp);
        const float4 b = *(const float4*)(sp + 4);
        const float4 c = *(const float4*)(sp + 8);
        const float4 d = *(const float4*)(sp + 12);
        half8 h0, h1;
        h0[0] = (_Float16)a.x; h0[1] = (_Float16)a.y; h0[2] = (_Float16)a.z; h0[3] = (_Float16)a.w;
        h0[4] = (_Float16)b.x; h0[5] = (_Float16)b.y; h0[6] = (_Float16)b.z; h0[7] = (_Float16)b.w;
        h1[0] = (_Float16)c.x; h1[1] = (_Float16)c.y; h1[2] = (_Float16)c.z; h1[3] = (_Float16)c.w;
        h1[4] = (_Float16)d.x; h1[5] = (_Float16)d.y; h1[6] = (_Float16)d.z; h1[7] = (_Float16)d.w;
        _Float16* dst = hsrc + (size_t)row * D + hoff;
        *(half8*)(dst)     = h0;
        *(half8*)(dst + 8) = h1;
    }
}

__global__ __launch_bounds__(BLOCK) void AggregationLayer_53051436040325_kernel(
    const _Float16* __restrict__ hsrc,
    const int*      __restrict__ gidx,
    const int*      __restrict__ start,
    float*          __restrict__ out,
    int N)
{
    const int n   = blockIdx.x * SEGS_PER_BLOCK + (threadIdx.x >> 2);  // segment id
    const int sub = threadIdx.x & (GSZ - 1);                           // 8-feature slot
    if (n >= N) return;

    const int lo = __builtin_nontemporal_load(start + n);
    const int hi = __builtin_nontemporal_load(start + n + 1);

    const _Float16* sp = hsrc + sub * 8;   // this lane's 16 B column offset

    float acc[8];
#pragma unroll
    for (int j = 0; j < 8; ++j) acc[j] = 0.f;

    int e = lo;
    // Unroll x8: vectorized idx loads (2 x dwordx4), 8 independent gather chains.
    for (; e + 8 <= hi; e += 8) {
        const int4a ga = __builtin_nontemporal_load((const int4a*)(gidx + e));
        const int4a gb = __builtin_nontemporal_load((const int4a*)(gidx + e + 4));
        half8 v[8];
#pragma unroll
        for (int k = 0; k < 4; ++k) v[k]     = *(const half8*)(sp + (size_t)ga[k] * D);
#pragma unroll
        for (int k = 0; k < 4; ++k) v[k + 4] = *(const half8*)(sp + (size_t)gb[k] * D);
#pragma unroll
        for (int k = 0; k < 8; ++k)
#pragma unroll
            for (int j = 0; j < 8; ++j) acc[j] += (float)v[k][j];
    }
    for (; e < hi; ++e) {
        const int g = __builtin_nontemporal_load(gidx + e);
        const half8 v = *(const half8*)(sp + (size_t)g * D);
#pragma unroll
        for (int j = 0; j < 8; ++j) acc[j] += (float)v[j];
    }

    const int c = hi - lo;
    const float inv = 1.f / (float)(c > 0 ? c : 1);    // max(count, 1)
    f32x4 r0 = { acc[0] * inv, acc[1] * inv, acc[2] * inv, acc[3] * inv };
    f32x4 r1 = { acc[4] * inv, acc[5] * inv, acc[6] * inv, acc[7] * inv };
    float* op = out + (size_t)n * D + sub * 8;
    __builtin_nontemporal_store(r0, (f32x4*)(op));
    __builtin_nontemporal_store(r1, (f32x4*)(op + 4));
}

extern "C" void kernel_launch(void* const* d_in, const int* in_sizes, int n_in,
                              void* d_out, int out_size, void* d_ws, size_t ws_size,
                              hipStream_t stream) {
    const float* src   = (const float*)d_in[0];
    const int*   gidx  = (const int*)d_in[1];
    const int*   segid = (const int*)d_in[2];
    const int E = in_sizes[1];
    const int N = in_sizes[0] / D;       // == out_size / D

    // ws layout: start[N+1] ints | hsrc[N*32] fp16 (6.4 MB)
    char* ws = (char*)d_ws;
    int* start = (int*)ws;
    size_t off = ((size_t)(N + 1) * sizeof(int) + 255) & ~(size_t)255;
    _Float16* hsrc = (_Float16*)(ws + off);

    float* out = (float*)d_out;

    const int threadsA = (E + 1 > 2 * N) ? (E + 1) : (2 * N);
    const int blocksA = (threadsA + BLOCK - 1) / BLOCK;
    prep_kernel<<<blocksA, BLOCK, 0, stream>>>(src, segid, start, hsrc, E, N);

    const int blocksB = (N + SEGS_PER_BLOCK - 1) / SEGS_PER_BLOCK;
    AggregationLayer_53051436040325_kernel<<<blocksB, BLOCK, 0, stream>>>(hsrc, gidx, start, out, N);
}

// Round 11
// 123.880 us; speedup vs baseline: 1.5086x; 1.0738x over previous
//
#include <hip/hip_runtime.h>
#include <hip/hip_fp16.h>

// AggregationLayer: out[n, :] = mean over {e : segment_ids[e]==n} of src[gather_idx[e], :]
// N=100000, E=3200000, D=32 fp32. segment_ids SORTED.
//
// R10 = R3 structure (proven best: 124.7 us total) + deeper MLP:
//  prep: segment boundaries start[n] + fp16 convert of src into ONE table (64 B rows).
//  main: 4-lane group per segment (4 x half8 = one coalesced 64 B line request per edge),
//        unroll x16 (16 independent gather chains/thread) + x8 tier + scalar tail.
//  NO nontemporal hints anywhere (R9 proved them a -14 us regression).

constexpr int D  = 32;
constexpr int GSZ = 4;                         // lanes per segment group
constexpr int BLOCK = 256;
constexpr int SEGS_PER_BLOCK = BLOCK / GSZ;    // 64 segments per block

typedef _Float16 half8 __attribute__((ext_vector_type(8)));
typedef int      int4a __attribute__((ext_vector_type(4)));

__global__ __launch_bounds__(BLOCK) void prep_kernel(
    const float* __restrict__ src,
    const int*   __restrict__ segid,
    int*         __restrict__ start,   // N+1 entries
    _Float16*    __restrict__ hsrc,    // N*32 halfs (64 B rows)
    int E, int N)
{
    const int t = blockIdx.x * BLOCK + threadIdx.x;

    // --- segment boundaries (one coalesced pass over segid) ---
    if (t <= E) {
        int s, p;
        if (t == E) { s = N; p = segid[E - 1]; }
        else        { s = segid[t]; p = (t == 0) ? -1 : segid[t - 1]; }
        for (int n = p + 1; n <= s; ++n) start[n] = t;   // usually 0 or 1 iters
    }

    // --- fp32 -> fp16 convert: thread t handles 16 features (32 B) ---
    if (t < 2 * N) {
        const int row  = t >> 1;
        const int hoff = (t & 1) * 16;
        const float* sp = src + (size_t)row * D + hoff;
        const float4 a = *(const float4*)(sp);
        const float4 b = *(const float4*)(sp + 4);
        const float4 c = *(const float4*)(sp + 8);
        const float4 d = *(const float4*)(sp + 12);
        half8 h0, h1;
        h0[0] = (_Float16)a.x; h0[1] = (_Float16)a.y; h0[2] = (_Float16)a.z; h0[3] = (_Float16)a.w;
        h0[4] = (_Float16)b.x; h0[5] = (_Float16)b.y; h0[6] = (_Float16)b.z; h0[7] = (_Float16)b.w;
        h1[0] = (_Float16)c.x; h1[1] = (_Float16)c.y; h1[2] = (_Float16)c.z; h1[3] = (_Float16)c.w;
        h1[4] = (_Float16)d.x; h1[5] = (_Float16)d.y; h1[6] = (_Float16)d.z; h1[7] = (_Float16)d.w;
        _Float16* dst = hsrc + (size_t)row * D + hoff;
        *(half8*)(dst)     = h0;
        *(half8*)(dst + 8) = h1;
    }
}

__global__ __launch_bounds__(BLOCK) void AggregationLayer_53051436040325_kernel(
    const _Float16* __restrict__ hsrc,
    const int*      __restrict__ gidx,
    const int*      __restrict__ start,
    float*          __restrict__ out,
    int N)
{
    const int n   = blockIdx.x * SEGS_PER_BLOCK + (threadIdx.x >> 2);  // segment id
    const int sub = threadIdx.x & (GSZ - 1);                           // 8-feature slot
    if (n >= N) return;

    const int lo = start[n];
    const int hi = start[n + 1];

    const _Float16* sp = hsrc + sub * 8;   // this lane's 16 B column offset

    float acc[8];
#pragma unroll
    for (int j = 0; j < 8; ++j) acc[j] = 0.f;

    int e = lo;
    // Tier 1: unroll x16 -> 16 independent idx->gather chains in flight.
    for (; e + 16 <= hi; e += 16) {
        int4a g[4];
#pragma unroll
        for (int k = 0; k < 4; ++k) g[k] = *(const int4a*)(gidx + e + 4 * k);
        half8 v[16];
#pragma unroll
        for (int k = 0; k < 16; ++k)
            v[k] = *(const half8*)(sp + (size_t)g[k >> 2][k & 3] * D);
#pragma unroll
        for (int k = 0; k < 16; ++k)
#pragma unroll
            for (int j = 0; j < 8; ++j) acc[j] += (float)v[k][j];
    }
    // Tier 2: unroll x8.
    for (; e + 8 <= hi; e += 8) {
        int4a g[2];
        g[0] = *(const int4a*)(gidx + e);
        g[1] = *(const int4a*)(gidx + e + 4);
        half8 v[8];
#pragma unroll
        for (int k = 0; k < 8; ++k)
            v[k] = *(const half8*)(sp + (size_t)g[k >> 2][k & 3] * D);
#pragma unroll
        for (int k = 0; k < 8; ++k)
#pragma unroll
            for (int j = 0; j < 8; ++j) acc[j] += (float)v[k][j];
    }
    // Tail: scalar.
    for (; e < hi; ++e) {
        const half8 v = *(const half8*)(sp + (size_t)gidx[e] * D);
#pragma unroll
        for (int j = 0; j < 8; ++j) acc[j] += (float)v[j];
    }

    const int c = hi - lo;
    const float inv = 1.f / (float)(c > 0 ? c : 1);    // max(count, 1)
    float4 r0 = make_float4(acc[0] * inv, acc[1] * inv, acc[2] * inv, acc[3] * inv);
    float4 r1 = make_float4(acc[4] * inv, acc[5] * inv, acc[6] * inv, acc[7] * inv);
    float* op = out + (size_t)n * D + sub * 8;
    *(float4*)(op)     = r0;
    *(float4*)(op + 4) = r1;
}

extern "C" void kernel_launch(void* const* d_in, const int* in_sizes, int n_in,
                              void* d_out, int out_size, void* d_ws, size_t ws_size,
                              hipStream_t stream) {
    const float* src   = (const float*)d_in[0];
    const int*   gidx  = (const int*)d_in[1];
    const int*   segid = (const int*)d_in[2];
    const int E = in_sizes[1];
    const int N = in_sizes[0] / D;       // == out_size / D

    // ws layout: start[N+1] ints | hsrc[N*32] fp16 (6.4 MB)
    char* ws = (char*)d_ws;
    int* start = (int*)ws;
    size_t off = ((size_t)(N + 1) * sizeof(int) + 255) & ~(size_t)255;
    _Float16* hsrc = (_Float16*)(ws + off);

    float* out = (float*)d_out;

    const int threadsA = (E + 1 > 2 * N) ? (E + 1) : (2 * N);
    const int blocksA = (threadsA + BLOCK - 1) / BLOCK;
    prep_kernel<<<blocksA, BLOCK, 0, stream>>>(src, segid, start, hsrc, E, N);

    const int blocksB = (N + SEGS_PER_BLOCK - 1) / SEGS_PER_BLOCK;
    AggregationLayer_53051436040325_kernel<<<blocksB, BLOCK, 0, stream>>>(hsrc, gidx, start, out, N);
}